// Round 8
// baseline (788.888 us; speedup 1.0000x reference)
//
#include <hip/hip_runtime.h>
#include <math.h>

// GCN 2-layer forward on MI355X — round 12.
//  Base = round 8 (best, 518 µs). Change: aggregation gathers made
//  L2-RESIDENT by column slicing.
//   * h stored slab-major hs[8][n][16] (3.2 MB/slab < 4 MB per-XCD L2);
//     k_agg1s runs 8 slice-passes in ONE dispatch (slice-major blockIdx) —
//     after warm-up every row-gather is an L2 hit instead of an L3 miss
//     (r9 PMC: 280 MB FETCH on a 25.6 MB working set = 84% L2 miss).
//   * g stored gs[3][n][16]; k_agg2s 3 slice-passes -> partial z[n][48];
//     k_smax streams z -> out1/out2 (log-softmax).
//   * gemm1/gemm2 epilogues write slabs directly (ct == slice index).
//  Dispatches: memset, d1(bhist∪prep), d2(bscan∪g1a), d3(part∪g1b),
//              d4(bsort∪g1c), agg1s, gemm2, agg2s, smax.

typedef unsigned int uint;
typedef unsigned short ushort_t;
using short8  = __attribute__((ext_vector_type(8))) short;
using float4v = __attribute__((ext_vector_type(4))) float;

__device__ __forceinline__ ushort_t f2bf(float f) {
    uint u = __float_as_uint(f);
    u += 0x7FFFu + ((u >> 16) & 1u);   // RNE
    return (ushort_t)(u >> 16);
}
__device__ __forceinline__ float2 unpack2(uint v) {
    return make_float2(__uint_as_float(v << 16), __uint_as_float(v & 0xFFFF0000u));
}
__device__ __forceinline__ uint pack2(float a, float b) {
    return (uint)f2bf(a) | ((uint)f2bf(b) << 16);
}

// ---- GEMM1 block body (RAW: no dinv), writes slab-major hs --------------
__device__ __forceinline__ void gemm1_block(int gb, const float* __restrict__ x,
                                            const ushort_t* __restrict__ W1t,
                                            ushort_t* __restrict__ hs, int n) {
    __shared__ ushort_t As[64][72];
    __shared__ ushort_t Bs[128][72];
    const int tid  = threadIdx.x;
    const int w    = tid >> 6, lane = tid & 63;
    const int quad = lane >> 4, l16 = lane & 15;
    const int row0 = gb * 64;
    const size_t n16 = (size_t)n * 16;

    float4v acc[8];
#pragma unroll
    for (int i = 0; i < 8; i++) acc[i] = (float4v)0.f;

    const int ar  = tid >> 2;
    const int akq = (tid & 3) * 16;
    const int br  = tid >> 1;
    const int bkq = (tid & 1) * 32;
    const int agrow = row0 + ar;
    const float* xp0 = &x[(size_t)agrow * 512];
    const ushort_t* wp0 = &W1t[(size_t)br * 512];

    for (int kb = 0; kb < 512; kb += 64) {
#pragma unroll
        for (int j = 0; j < 4; j++) {
            float4 v = make_float4(0.f, 0.f, 0.f, 0.f);
            if (agrow < n) v = *(const float4*)(xp0 + kb + akq + j * 4);
            ushort4 b;
            b.x = f2bf(v.x); b.y = f2bf(v.y); b.z = f2bf(v.z); b.w = f2bf(v.w);
            *(ushort4*)&As[ar][akq + j * 4] = b;
        }
#pragma unroll
        for (int j = 0; j < 8; j++) {
            *(ushort4*)&Bs[br][bkq + j * 4] = *(const ushort4*)(wp0 + kb + bkq + j * 4);
        }
        __syncthreads();
#pragma unroll
        for (int ks = 0; ks < 64; ks += 32) {
            short8 a = *(const short8*)&As[w * 16 + l16][ks + quad * 8];
#pragma unroll
            for (int ct = 0; ct < 8; ct++) {
                short8 b = *(const short8*)&Bs[ct * 16 + l16][ks + quad * 8];
                acc[ct] = __builtin_amdgcn_mfma_f32_16x16x32_bf16(a, b, acc[ct], 0, 0, 0);
            }
        }
        __syncthreads();
    }
#pragma unroll
    for (int r = 0; r < 4; r++) {
        int grow = row0 + w * 16 + quad * 4 + r;
        if (grow >= n) continue;
#pragma unroll
        for (int ct = 0; ct < 8; ct++) {
            hs[(size_t)ct * n16 + (size_t)grow * 16 + l16] = f2bf(acc[ct][r]);
        }
    }
}

// ---- D1: bhist (blocks < nblkA) ∪ weight prep ---------------------------
__global__ __launch_bounds__(256) void k_d1(const int* __restrict__ dst,
                                            int* __restrict__ bcnt, int e, int nb, int nblkA,
                                            const float* __restrict__ W1,
                                            const float* __restrict__ W2,
                                            ushort_t* __restrict__ W1t,
                                            ushort_t* __restrict__ W2t) {
    if ((int)blockIdx.x >= nblkA) {
        int idx = ((int)blockIdx.x - nblkA) * 256 + threadIdx.x;   // 71680 threads
        if (idx < 65536) {
            int nn = idx >> 9, k = idx & 511;
            W1t[idx] = f2bf(W1[(size_t)k * 128 + nn]);
        } else if (idx < 71680) {
            int j = idx - 65536;
            int c = j >> 7, k = j & 127;
            W2t[j] = (c < 40) ? f2bf(W2[(size_t)k * 40 + c]) : (ushort_t)0;
        }
        return;
    }
    __shared__ int sh[800];
    for (int t = threadIdx.x; t < nb; t += 256) sh[t] = 0;
    __syncthreads();
    int ibase = blockIdx.x * 2560 + threadIdx.x;
#pragma unroll
    for (int j = 0; j < 10; j++) {
        int i = ibase + j * 256;
        if (i < e) atomicAdd(&sh[dst[i] >> 7], 1);
    }
    __syncthreads();
    for (int t = threadIdx.x; t < nb; t += 256) {
        int c = sh[t];
        if (c) atomicAdd(&bcnt[t], c);
    }
}

// ---- D2: bscan (block 0) ∪ gemm1 chunk ----------------------------------
__global__ __launch_bounds__(256) void k_d2(const int* __restrict__ bcnt, int* __restrict__ bbase,
                                            int* __restrict__ bcur, int* __restrict__ row_ptr,
                                            int nb, int n, int e,
                                            const float* __restrict__ x,
                                            const ushort_t* __restrict__ W1t,
                                            ushort_t* __restrict__ hs, int goff) {
    if (blockIdx.x > 0) {
        gemm1_block((int)blockIdx.x - 1 + goff, x, W1t, hs, n);
        return;
    }
    __shared__ int sd[256];
    int t = threadIdx.x;
    int base = t * 4;
    int v[4];
#pragma unroll
    for (int j = 0; j < 4; j++) v[j] = (base + j < nb) ? bcnt[base + j] : 0;
    int s0 = v[0], s1 = s0 + v[1], s2 = s1 + v[2], s3 = s2 + v[3];
    sd[t] = s3;
    __syncthreads();
    for (int d = 1; d < 256; d <<= 1) {
        int xv = (t >= d) ? sd[t - d] : 0;
        __syncthreads();
        sd[t] += xv;
        __syncthreads();
    }
    int excl = sd[t] - s3;
    int pre0 = excl, pre1 = excl + s0, pre2 = excl + s1, pre3 = excl + s2;
    if (base + 0 < nb) { bbase[base + 0] = pre0; bcur[base + 0] = pre0; }
    if (base + 1 < nb) { bbase[base + 1] = pre1; bcur[base + 1] = pre1; }
    if (base + 2 < nb) { bbase[base + 2] = pre2; bcur[base + 2] = pre2; }
    if (base + 3 < nb) { bbase[base + 3] = pre3; bcur[base + 3] = pre3; }
    if (t == 255) bbase[nb] = excl + s3;   // == e
    if (t == 0) row_ptr[n] = e;
}

// ---- D3: part (blocks < nblkA) ∪ gemm1 chunk ----------------------------
__global__ __launch_bounds__(256) void k_d3(const int* __restrict__ src, const int* __restrict__ dst,
                                            int* __restrict__ bcur, uint* __restrict__ pbuf,
                                            int e, int nb, int nblkA,
                                            const float* __restrict__ x,
                                            const ushort_t* __restrict__ W1t,
                                            ushort_t* __restrict__ hs, int n, int goff) {
    if ((int)blockIdx.x >= nblkA) {
        gemm1_block((int)blockIdx.x - nblkA + goff, x, W1t, hs, n);
        return;
    }
    __shared__ int sh[800];
    __shared__ int base_l[800];
    for (int t = threadIdx.x; t < nb; t += 256) sh[t] = 0;
    __syncthreads();
    uint pk[10]; int bk[10]; int lp[10];
    int ibase = blockIdx.x * 2560 + threadIdx.x;
#pragma unroll
    for (int j = 0; j < 10; j++) {
        int i = ibase + j * 256;
        bk[j] = -1;
        if (i < e) {
            int s = src[i], d = dst[i];
            int b = d >> 7;
            bk[j] = b;
            pk[j] = ((uint)(d & 127) << 25) | (uint)s;
            lp[j] = atomicAdd(&sh[b], 1);
        }
    }
    __syncthreads();
    for (int t = threadIdx.x; t < nb; t += 256) {
        int c = sh[t];
        base_l[t] = c ? atomicAdd(&bcur[t], c) : 0;
    }
    __syncthreads();
#pragma unroll
    for (int j = 0; j < 10; j++) {
        if (bk[j] >= 0) pbuf[base_l[bk[j]] + lp[j]] = pk[j];
    }
}

// ---- D4: bsort (blocks < NB) ∪ gemm1 chunk ------------------------------
__global__ __launch_bounds__(256) void k_d4(const uint* __restrict__ pbuf,
                                            const int* __restrict__ bbase,
                                            float* __restrict__ dinv,
                                            int* __restrict__ row_ptr,
                                            int* __restrict__ es_src, int n, int nb,
                                            const float* __restrict__ x,
                                            const ushort_t* __restrict__ W1t,
                                            ushort_t* __restrict__ hs, int goff) {
    if ((int)blockIdx.x >= nb) {
        gemm1_block((int)blockIdx.x - nb + goff, x, W1t, hs, n);
        return;
    }
    __shared__ int cl[128];
    __shared__ int cur[128];
    const int b = blockIdx.x;
    const int tid = threadIdx.x;
    const int ebeg = bbase[b], eend = bbase[b + 1];
    const int m = eend - ebeg;
    if (tid < 128) cl[tid] = 0;
    __syncthreads();
    for (int i = tid; i < m; i += 256) {
        uint p = pbuf[ebeg + i];
        atomicAdd(&cl[p >> 25], 1);
    }
    __syncthreads();
    int own = (tid < 128) ? cl[tid] : 0;
    for (int d = 1; d < 128; d <<= 1) {
        int v = 0;
        if (tid < 128 && tid >= d) v = cl[tid - d];
        __syncthreads();
        if (tid < 128 && tid >= d) cl[tid] += v;
        __syncthreads();
    }
    if (tid < 128) {
        int excl = cl[tid] - own;
        int node = b * 128 + tid;
        if (node < n) {
            dinv[node] = rsqrtf((float)(own + 1));   // deg incl. self-loop
            row_ptr[node] = ebeg + excl;
        }
        cur[tid] = excl;
    }
    __syncthreads();
    for (int i = tid; i < m; i += 256) {
        uint p = pbuf[ebeg + i];
        int dl = (int)(p >> 25);
        int pos = atomicAdd(&cur[dl], 1);
        es_src[ebeg + pos] = (int)(p & 0x1FFFFFFu);
    }
}

// ---- agg1 sliced: 8 slice-passes over hs slabs (L2-resident) ------------
// grid = 8*sb blocks, slice-major. Block=4 waves, wave=4 nodes.
// Per node: 8 groups x 8 lanes, lane loads 1 dword (2 cols) per edge.
__global__ __launch_bounds__(256) void k_agg1s(const ushort_t* __restrict__ hs,
                                               const int* __restrict__ row_ptr,
                                               const int* __restrict__ es_src,
                                               const float* __restrict__ dinv,
                                               const float* __restrict__ b1,
                                               uint* __restrict__ h1, int n, int sb) {
    const int tid  = threadIdx.x;
    const int wv   = tid >> 6;
    const int lane = tid & 63;
    const int g8   = lane >> 3;
    const int l8   = lane & 7;
    const int s    = blockIdx.x / sb;                 // slice 0..7
    const int nb0  = (blockIdx.x % sb) * 16 + wv * 4; // first node of this wave
    const uint* hp = (const uint*)(hs + (size_t)s * (size_t)n * 16);  // slab, 8 uints/row
    const float bb0 = b1[s * 16 + l8 * 2];
    const float bb1 = b1[s * 16 + l8 * 2 + 1];

    for (int i = 0; i < 4; i++) {
        const int node = nb0 + i;
        if (node >= n) return;
        const int k0 = row_ptr[node], k1 = row_ptr[node + 1];
        const float di = dinv[node];
        uint sv = hp[(size_t)node * 8 + l8];          // self, early (L2 hit)

        float ax = 0.f, ay = 0.f;
        int k = k0 + g8;
        for (; k + 8 < k1; k += 16) {                 // 16 edges per wave iter
            int s0 = __builtin_nontemporal_load(&es_src[k]);
            int s1 = __builtin_nontemporal_load(&es_src[k + 8]);
            float d0 = dinv[s0], d1 = dinv[s1];
            uint u0 = hp[(size_t)s0 * 8 + l8];
            uint u1 = hp[(size_t)s1 * 8 + l8];
            float2 f0 = unpack2(u0), f1 = unpack2(u1);
            ax = fmaf(d0, f0.x, ax); ay = fmaf(d0, f0.y, ay);
            ax = fmaf(d1, f1.x, ax); ay = fmaf(d1, f1.y, ay);
        }
        for (; k < k1; k += 8) {
            int s0 = __builtin_nontemporal_load(&es_src[k]);
            float d0 = dinv[s0];
            float2 f0 = unpack2(hp[(size_t)s0 * 8 + l8]);
            ax = fmaf(d0, f0.x, ax); ay = fmaf(d0, f0.y, ay);
        }
        // combine 8 groups
        ax += __shfl_xor(ax, 8);  ay += __shfl_xor(ay, 8);
        ax += __shfl_xor(ax, 16); ay += __shfl_xor(ay, 16);
        ax += __shfl_xor(ax, 32); ay += __shfl_xor(ay, 32);
        float2 sf = unpack2(sv);
        ax = fmaf(di, sf.x, ax); ay = fmaf(di, sf.y, ay);   // self, once

        float r0 = di * ax + bb0;
        float r1 = di * ay + bb1;
        r0 = r0 > 0.f ? r0 : 0.f;
        r1 = r1 > 0.f ? r1 : 0.f;
        if (g8 == 0) h1[(size_t)node * 64 + s * 8 + l8] = pack2(r0, r1);
    }
}

// ---- GEMM2 (MFMA bf16): gs[ct][i][16] = bf16(dinv[i]*(h1@W2)) -----------
__global__ __launch_bounds__(256) void k_gemm2(const ushort_t* __restrict__ h1,
                                               const ushort_t* __restrict__ W2t,
                                               const float* __restrict__ dinv,
                                               ushort_t* __restrict__ gs, int n) {
    __shared__ ushort_t As[64][136];
    __shared__ ushort_t Bs[48][136];
    const int tid  = threadIdx.x;
    const int w    = tid >> 6, lane = tid & 63;
    const int quad = lane >> 4, l16 = lane & 15;
    const int row0 = blockIdx.x * 64;
    const size_t n16 = (size_t)n * 16;

    {
        int ar = tid >> 2;
        int ak = (tid & 3) * 32;
        int grow = row0 + ar;
#pragma unroll
        for (int j = 0; j < 4; j++) {
            uint4 v = make_uint4(0, 0, 0, 0);
            if (grow < n) v = *(const uint4*)&h1[(size_t)grow * 128 + ak + j * 8];
            *(uint4*)&As[ar][ak + j * 8] = v;
        }
    }
    for (int i = tid; i < 768; i += 256) {
        int row = i >> 4, q = i & 15;
        *(uint4*)&Bs[row][q * 8] = *(const uint4*)&W2t[(size_t)row * 128 + q * 8];
    }
    __syncthreads();

    float4v acc[3];
#pragma unroll
    for (int i = 0; i < 3; i++) acc[i] = (float4v)0.f;
#pragma unroll
    for (int ks = 0; ks < 128; ks += 32) {
        short8 a = *(const short8*)&As[w * 16 + l16][ks + quad * 8];
#pragma unroll
        for (int ct = 0; ct < 3; ct++) {
            short8 b = *(const short8*)&Bs[ct * 16 + l16][ks + quad * 8];
            acc[ct] = __builtin_amdgcn_mfma_f32_16x16x32_bf16(a, b, acc[ct], 0, 0, 0);
        }
    }
#pragma unroll
    for (int r = 0; r < 4; r++) {
        int grow = row0 + w * 16 + quad * 4 + r;
        if (grow >= n) continue;
        float di = dinv[grow];
#pragma unroll
        for (int ct = 0; ct < 3; ct++) {
            gs[(size_t)ct * n16 + (size_t)grow * 16 + l16] = f2bf(di * acc[ct][r]);
        }
    }
}

// ---- agg2 sliced: 3 slice-passes over gs slabs -> partial z[n][48] ------
__global__ __launch_bounds__(256) void k_agg2s(const ushort_t* __restrict__ gs,
                                               const int* __restrict__ row_ptr,
                                               const int* __restrict__ es_src,
                                               const float* __restrict__ dinv,
                                               const float* __restrict__ b2,
                                               float* __restrict__ z, int n, int sb) {
    const int tid  = threadIdx.x;
    const int wv   = tid >> 6;
    const int lane = tid & 63;
    const int g8   = lane >> 3;
    const int l8   = lane & 7;
    const int s    = blockIdx.x / sb;                 // slice 0..2
    const int nb0  = (blockIdx.x % sb) * 16 + wv * 4;
    const uint* gp = (const uint*)(gs + (size_t)s * (size_t)n * 16);
    const int col0 = s * 16 + l8 * 2;
    const float bb0 = (col0     < 40) ? b2[col0]     : 0.f;
    const float bb1 = (col0 + 1 < 40) ? b2[col0 + 1] : 0.f;

    for (int i = 0; i < 4; i++) {
        const int node = nb0 + i;
        if (node >= n) return;
        const int k0 = row_ptr[node], k1 = row_ptr[node + 1];
        const float di = dinv[node];
        uint sv = gp[(size_t)node * 8 + l8];          // self (g has dinv[src] folded)

        float ax = 0.f, ay = 0.f;
        int k = k0 + g8;
        for (; k + 8 < k1; k += 16) {
            int s0 = __builtin_nontemporal_load(&es_src[k]);
            int s1 = __builtin_nontemporal_load(&es_src[k + 8]);
            uint u0 = gp[(size_t)s0 * 8 + l8];
            uint u1 = gp[(size_t)s1 * 8 + l8];
            float2 f0 = unpack2(u0), f1 = unpack2(u1);
            ax += f0.x + f1.x;
            ay += f0.y + f1.y;
        }
        for (; k < k1; k += 8) {
            int s0 = __builtin_nontemporal_load(&es_src[k]);
            float2 f0 = unpack2(gp[(size_t)s0 * 8 + l8]);
            ax += f0.x;
            ay += f0.y;
        }
        ax += __shfl_xor(ax, 8);  ay += __shfl_xor(ay, 8);
        ax += __shfl_xor(ax, 16); ay += __shfl_xor(ay, 16);
        ax += __shfl_xor(ax, 32); ay += __shfl_xor(ay, 32);
        float2 sf = unpack2(sv);
        ax += sf.x; ay += sf.y;                        // self, once

        float v0 = di * ax + bb0;
        float v1 = di * ay + bb1;
        if (g8 == 0) *(float2*)&z[(size_t)node * 48 + col0] = make_float2(v0, v1);
    }
}

// ---- log-softmax over z[n][48] (40 real cols) -> out1, out2 -------------
__global__ __launch_bounds__(256) void k_smax(const float* __restrict__ z,
                                              float* __restrict__ out1,
                                              float* __restrict__ out2, int n) {
    const int tid  = threadIdx.x;
    const int node = blockIdx.x * 4 + (tid >> 6);
    if (node >= n) return;
    const int lane = tid & 63;

    float v = (lane < 40) ? z[(size_t)node * 48 + lane] : -1e30f;
    float m = v;
#pragma unroll
    for (int d = 1; d < 64; d <<= 1) m = fmaxf(m, __shfl_xor(m, d));
    float ex = (lane < 40) ? expf(v - m) : 0.f;
    float ssum = ex;
#pragma unroll
    for (int d = 1; d < 64; d <<= 1) ssum += __shfl_xor(ssum, d);
    float ls = logf(ssum) + m;

    if (lane < 40) {
        out1[(size_t)node * 40 + lane] = v;
        out2[(size_t)node * 40 + lane] = v - ls;
    }
}

static inline size_t align4(size_t v) { return (v + 3) & ~(size_t)3; }

extern "C" void kernel_launch(void* const* d_in, const int* in_sizes, int n_in,
                              void* d_out, int out_size, void* d_ws, size_t ws_size,
                              hipStream_t stream) {
    const float* x  = (const float*)d_in[0];
    const int*   ei = (const int*)d_in[1];
    const float* W1 = (const float*)d_in[2];
    const float* b1 = (const float*)d_in[3];
    const float* W2 = (const float*)d_in[4];
    const float* b2 = (const float*)d_in[5];

    const int n = in_sizes[0] / 512;
    const int e = in_sizes[1] / 2;
    const int* src = ei;
    const int* dst = ei + e;
    const int NB = (n + 127) >> 7;           // buckets of 128 nodes (<=800)

    char* p = (char*)d_ws;
    int*      bcnt    = (int*)p;        p += align4(NB) * 4;
    int*      bbase   = (int*)p;        p += align4(NB + 1) * 4;
    int*      bcur    = (int*)p;        p += align4(NB) * 4;
    int*      row_ptr = (int*)p;        p += align4(n + 1) * 4;
    float*    dinv    = (float*)p;      p += align4(n) * 4;
    uint*     pbuf    = (uint*)p;       p += align4(e) * 4;
    int*      es_src  = (int*)p;        p += align4(e) * 4;
    ushort_t* W1t     = (ushort_t*)p;   p += (size_t)128 * 512 * 2;
    ushort_t* W2t     = (ushort_t*)p;   p += (size_t)48 * 128 * 2;
    ushort_t* hs      = (ushort_t*)p;   p += (size_t)n * 128 * 2;   // [8][n][16] slabs
    ushort_t* h1      = (ushort_t*)p;   p += (size_t)n * 128 * 2;   // [n][128] row-major
    ushort_t* gs      = (ushort_t*)p;   p += (size_t)n * 48 * 2;    // [3][n][16] slabs
    float*    z       = (float*)p;      p += (size_t)n * 48 * 4;    // [n][48] partials
    float*    out1    = (float*)d_out;
    float*    out2    = out1 + (size_t)n * 40;

    const int B = 256;
    const int nblkA = (e + 2559) / 2560;
    const int NG = (n + 63) / 64;           // gemm1 blocks total
    const int c  = (NG + 2) / 3;            // chunk size (thirds)
    const int c2 = NG - 2 * c;              // last chunk
    const int SB = (n + 15) >> 4;           // blocks per slice (16 nodes/block)

    hipMemsetAsync(bcnt, 0, (size_t)NB * 4, stream);

    // CSR build overlapped with weight prep + gemm1 thirds
    k_d1<<<nblkA + 280, B, 0, stream>>>(dst, bcnt, e, NB, nblkA, W1, W2, W1t, W2t);
    k_d2<<<1 + c, B, 0, stream>>>(bcnt, bbase, bcur, row_ptr, NB, n, e, x, W1t, hs, 0);
    k_d3<<<nblkA + c, B, 0, stream>>>(src, dst, bcur, pbuf, e, NB, nblkA, x, W1t, hs, n, c);
    k_d4<<<NB + c2, B, 0, stream>>>(pbuf, bbase, dinv, row_ptr, es_src, n, NB, x, W1t, hs, 2 * c);

    // layer 1 aggregation: 8 L2-resident slice passes (one dispatch)
    k_agg1s<<<8 * SB, B, 0, stream>>>(hs, row_ptr, es_src, dinv, b1, (uint*)h1, n, SB);

    // layer 2
    k_gemm2<<<(n + 63) / 64, B, 0, stream>>>(h1, W2t, dinv, gs, n);
    k_agg2s<<<3 * SB, B, 0, stream>>>(gs, row_ptr, es_src, dinv, b2, z, n, SB);
    k_smax<<<(n + 3) / 4, B, 0, stream>>>(z, out1, out2, n);
}